// Round 1
// baseline (478.047 us; speedup 1.0000x reference)
//
#include <hip/hip_runtime.h>
#include <math.h>

// ---------------------------------------------------------------------------
// QuantumModel fused forward.
//   out = (((LN(relu(x@W1+b1)))@W2+b2 -> tanh -> angles -> 4-qubit product
//          state psi) @ U^T -> |.|^2 -> @SIGNS) @ post_w + post_b
// U (16x16 complex) depends only on weights -> built once per launch by a
// tiny 1-block kernel. SIGNS@post_w folded into Q (16x2).
// ---------------------------------------------------------------------------

__device__ float g_Ur[256];   // Re(U), row-major 16x16
__device__ float g_Ui[256];   // Im(U)
__device__ float g_Q[32];     // Q[j][t] = sum_i SIGNS[j][i]*post_w[i][t]

// --------------------------- setup kernel ----------------------------------
__global__ void build_unitary(const float* __restrict__ shared_w,
                              const float* __restrict__ task_w,
                              const float* __restrict__ post_w) {
  __shared__ float Ur[16][16];
  __shared__ float Ui[16][16];
  const int tid = threadIdx.x;        // 256 threads
  const int r = tid >> 4, c = tid & 15;
  Ur[r][c] = (r == c) ? 1.0f : 0.0f;
  Ui[r][c] = 0.0f;
  __syncthreads();

  for (int layer = 0; layer < 3; ++layer) {
    const float* w = (layer < 2) ? (shared_w + layer * 12) : task_w;
    const int lmod = (layer < 2) ? layer : 0;

    // 4 single-qubit Rot gates (left-multiply, qubit q acts on bit (3-q))
    for (int q = 0; q < 4; ++q) {
      const float phi = w[q * 3 + 0], theta = w[q * 3 + 1], omega = w[q * 3 + 2];
      const float ch = cosf(theta * 0.5f), sh = sinf(theta * 0.5f);
      const float ap = -0.5f * (phi + omega);   // m00 = e^{i*ap}*ch, m11 = conj
      const float am = 0.5f * (phi - omega);    // m01 = -e^{i*am}*sh, m10 = e^{-i*am}*sh
      const float cap = cosf(ap), sap = sinf(ap);
      const float cam = cosf(am), sam = sinf(am);
      const int mask = 1 << (3 - q);
      const int rp = r ^ mask;
      const bool hi = (r & mask) != 0;
      const float a_r = Ur[r][c],  a_i = Ui[r][c];    // this row (old)
      const float b_r = Ur[rp][c], b_i = Ui[rp][c];   // partner row (old)
      __syncthreads();
      float nr, ni;
      if (!hi) {  // new_r0 = m00*a + m01*b
        nr = ch * (cap * a_r - sap * a_i) - sh * (cam * b_r - sam * b_i);
        ni = ch * (cap * a_i + sap * a_r) - sh * (cam * b_i + sam * b_r);
      } else {    // new_r1 = m10*b + m11*a
        nr = sh * (cam * b_r + sam * b_i) + ch * (cap * a_r + sap * a_i);
        ni = sh * (cam * b_i - sam * b_r) + ch * (cap * a_i - sap * a_r);
      }
      Ur[r][c] = nr; Ui[r][c] = ni;
      __syncthreads();
    }

    // ring of CNOTs: control i, target (i+rr)%4. CNOT row map is an
    // involution, so new[j,:] = old[f(j),:] with f(j) = j^tbit if control set.
    const int rr = lmod % 3 + 1;
    for (int q = 0; q < 4; ++q) {
      const int cbit = 1 << (3 - q);
      const int tbit = 1 << (3 - ((q + rr) & 3));
      const int src = (r & cbit) ? (r ^ tbit) : r;
      const float a_r = Ur[src][c], a_i = Ui[src][c];
      __syncthreads();
      Ur[r][c] = a_r; Ui[r][c] = a_i;
      __syncthreads();
    }
  }

  g_Ur[tid] = Ur[r][c];
  g_Ui[tid] = Ui[r][c];
  if (tid < 32) {                 // Q[j][t], j = tid>>1, t = tid&1
    const int j = tid >> 1, t = tid & 1;
    float acc = 0.0f;
    for (int i = 0; i < 4; ++i) {
      const float sgn = ((j >> (3 - i)) & 1) ? -1.0f : 1.0f;
      acc += sgn * post_w[i * 2 + t];
    }
    g_Q[tid] = acc;
  }
}

// --------------------------- main fused kernel -----------------------------
__global__ __launch_bounds__(256) void qm_fused(
    const float* __restrict__ x,
    const float* __restrict__ w1,   // (784,32) row-major
    const float* __restrict__ b1,   // (32,)
    const float* __restrict__ lg,   // ln_g
    const float* __restrict__ lb,   // ln_b
    const float* __restrict__ w2,   // (32,4) row-major
    const float* __restrict__ b2,   // (4,)
    const float* __restrict__ pb,   // post_b (2,)
    float* __restrict__ out,        // (B,2)
    int B) {
  const int r = blockIdx.x * 256 + threadIdx.x;
  if (r >= B) return;

  const float4* __restrict__ xr =
      reinterpret_cast<const float4*>(x + (size_t)r * 784);

  float acc[32];
#pragma unroll
  for (int h = 0; h < 32; ++h) acc[h] = 0.0f;

  // --- encoder GEMM: 784 k-steps, 16 k per iteration, manual prefetch ---
  float4 p0 = xr[0], p1 = xr[1], p2 = xr[2], p3 = xr[3];
#pragma unroll 1
  for (int it = 0; it < 49; ++it) {
    const float4 u0 = p0, u1 = p1, u2 = p2, u3 = p3;
    if (it < 48) {
      const int nb = (it + 1) * 4;
      p0 = xr[nb]; p1 = xr[nb + 1]; p2 = xr[nb + 2]; p3 = xr[nb + 3];
    }
    const float xs[16] = {u0.x, u0.y, u0.z, u0.w, u1.x, u1.y, u1.z, u1.w,
                          u2.x, u2.y, u2.z, u2.w, u3.x, u3.y, u3.z, u3.w};
    const float* __restrict__ wk = w1 + it * (16 * 32);   // wave-uniform
#pragma unroll
    for (int kk = 0; kk < 16; ++kk) {
      const float xv = xs[kk];
#pragma unroll
      for (int h = 0; h < 32; ++h)
        acc[h] = fmaf(wk[kk * 32 + h], xv, acc[h]);       // s_load weights
    }
  }

  // --- bias + relu + layernorm ---
  float mu = 0.0f, sq = 0.0f;
#pragma unroll
  for (int h = 0; h < 32; ++h) {
    float v = fmaxf(acc[h] + b1[h], 0.0f);
    acc[h] = v;
    mu += v;
    sq += v * v;
  }
  mu *= (1.0f / 32.0f);
  sq *= (1.0f / 32.0f);
  const float inv = rsqrtf(sq - mu * mu + 1e-5f);

  // --- z = tanh(hn @ W2 + b2); angles; single-qubit states ---
  float z[4] = {b2[0], b2[1], b2[2], b2[3]};
#pragma unroll
  for (int h = 0; h < 32; ++h) {
    const float hn = (acc[h] - mu) * inv * lg[h] + lb[h];
#pragma unroll
    for (int j = 0; j < 4; ++j) z[j] = fmaf(hn, w2[h * 4 + j], z[j]);
  }
  float cq[4], sn[4];
#pragma unroll
  for (int j = 0; j < 4; ++j) {
    const float half = tanhf(z[j]) * 1.5707963267948966f;
    __sincosf(half, &sn[j], &cq[j]);
  }

  // --- psi: 4-fold kron, qubit 0 = MSB ---
  float psi[16];
#pragma unroll
  for (int b = 0; b < 16; ++b) {
    float p = ((b >> 3) & 1) ? sn[0] : cq[0];
    p *= ((b >> 2) & 1) ? sn[1] : cq[1];
    p *= ((b >> 1) & 1) ? sn[2] : cq[2];
    p *= (b & 1) ? sn[3] : cq[3];
    psi[b] = p;
  }

  // --- probs -> expz -> post head, all folded: out_t = sum_j Q[j][t]*|U_j.psi|^2
  float o0 = pb[0], o1 = pb[1];
#pragma unroll
  for (int j = 0; j < 16; ++j) {
    float re = 0.0f, im = 0.0f;
#pragma unroll
    for (int k = 0; k < 16; ++k) {
      re = fmaf(g_Ur[j * 16 + k], psi[k], re);
      im = fmaf(g_Ui[j * 16 + k], psi[k], im);
    }
    const float p = re * re + im * im;
    o0 = fmaf(g_Q[j * 2 + 0], p, o0);
    o1 = fmaf(g_Q[j * 2 + 1], p, o1);
  }
  reinterpret_cast<float2*>(out)[r] = make_float2(o0, o1);
}

// --------------------------- launcher --------------------------------------
extern "C" void kernel_launch(void* const* d_in, const int* in_sizes, int n_in,
                              void* d_out, int out_size, void* d_ws, size_t ws_size,
                              hipStream_t stream) {
  const float* x  = (const float*)d_in[0];
  const float* w1 = (const float*)d_in[1];
  const float* b1 = (const float*)d_in[2];
  const float* lg = (const float*)d_in[3];
  const float* lb = (const float*)d_in[4];
  const float* w2 = (const float*)d_in[5];
  const float* b2 = (const float*)d_in[6];
  const float* sw = (const float*)d_in[7];
  const float* tw = (const float*)d_in[8];
  const float* pw = (const float*)d_in[9];
  const float* pb = (const float*)d_in[10];
  float* out = (float*)d_out;

  const int B = in_sizes[0] / 784;

  hipLaunchKernelGGL(build_unitary, dim3(1), dim3(256), 0, stream, sw, tw, pw);
  hipLaunchKernelGGL(qm_fused, dim3((B + 255) / 256), dim3(256), 0, stream,
                     x, w1, b1, lg, lb, w2, b2, pb, out, B);
}

// Round 2
// 372.618 us; speedup vs baseline: 1.2829x; 1.2829x over previous
//
#include <hip/hip_runtime.h>
#include <math.h>

// ---------------------------------------------------------------------------
// QuantumModel fused forward, v2: split-K=4 + LDS weight broadcast.
//   out = (((LN(relu(x@W1+b1)))@W2+b2 -> tanh -> angles -> 4-qubit product
//          state psi) @ U^T -> |.|^2 -> @SIGNS) @ post_w + post_b
// U (16x16 complex) depends only on weights -> built once per launch by a
// tiny 1-block kernel. SIGNS@post_w folded into Q (16x2).
// ---------------------------------------------------------------------------

__device__ float g_Ur[256];   // Re(U), row-major 16x16
__device__ float g_Ui[256];   // Im(U)
__device__ float g_Q[32];     // Q[j][t] = sum_i SIGNS[j][i]*post_w[i][t]

// --------------------------- setup kernel ----------------------------------
__global__ void build_unitary(const float* __restrict__ shared_w,
                              const float* __restrict__ task_w,
                              const float* __restrict__ post_w) {
  __shared__ float Ur[16][16];
  __shared__ float Ui[16][16];
  const int tid = threadIdx.x;        // 256 threads
  const int r = tid >> 4, c = tid & 15;
  Ur[r][c] = (r == c) ? 1.0f : 0.0f;
  Ui[r][c] = 0.0f;
  __syncthreads();

  for (int layer = 0; layer < 3; ++layer) {
    const float* w = (layer < 2) ? (shared_w + layer * 12) : task_w;
    const int lmod = (layer < 2) ? layer : 0;

    for (int q = 0; q < 4; ++q) {
      const float phi = w[q * 3 + 0], theta = w[q * 3 + 1], omega = w[q * 3 + 2];
      const float ch = cosf(theta * 0.5f), sh = sinf(theta * 0.5f);
      const float ap = -0.5f * (phi + omega);
      const float am = 0.5f * (phi - omega);
      const float cap = cosf(ap), sap = sinf(ap);
      const float cam = cosf(am), sam = sinf(am);
      const int mask = 1 << (3 - q);
      const int rp = r ^ mask;
      const bool hi = (r & mask) != 0;
      const float a_r = Ur[r][c],  a_i = Ui[r][c];
      const float b_r = Ur[rp][c], b_i = Ui[rp][c];
      __syncthreads();
      float nr, ni;
      if (!hi) {
        nr = ch * (cap * a_r - sap * a_i) - sh * (cam * b_r - sam * b_i);
        ni = ch * (cap * a_i + sap * a_r) - sh * (cam * b_i + sam * b_r);
      } else {
        nr = sh * (cam * b_r + sam * b_i) + ch * (cap * a_r + sap * a_i);
        ni = sh * (cam * b_i - sam * b_r) + ch * (cap * a_i - sap * a_r);
      }
      Ur[r][c] = nr; Ui[r][c] = ni;
      __syncthreads();
    }

    const int rr = lmod % 3 + 1;
    for (int q = 0; q < 4; ++q) {
      const int cbit = 1 << (3 - q);
      const int tbit = 1 << (3 - ((q + rr) & 3));
      const int src = (r & cbit) ? (r ^ tbit) : r;
      const float a_r = Ur[src][c], a_i = Ui[src][c];
      __syncthreads();
      Ur[r][c] = a_r; Ui[r][c] = a_i;
      __syncthreads();
    }
  }

  g_Ur[tid] = Ur[r][c];
  g_Ui[tid] = Ui[r][c];
  if (tid < 32) {
    const int j = tid >> 1, t = tid & 1;
    float acc = 0.0f;
    for (int i = 0; i < 4; ++i) {
      const float sgn = ((j >> (3 - i)) & 1) ? -1.0f : 1.0f;
      acc += sgn * post_w[i * 2 + t];
    }
    g_Q[tid] = acc;
  }
}

// --------------------------- main fused kernel -----------------------------
// Block: 512 threads = 8 waves. Wave w: chunk = w>>1 (k range of 196),
// rows = (w&1)*64 + lane, i.e. block covers 128 rows x 4 k-chunks.
// Grid: B/128 blocks -> 2 blocks/CU, 16 waves/CU.
#define RPB 128          // rows per block
#define KCH 196          // k per chunk (784/4)
#define NMICRO 49        // 4 k per micro-iteration

__global__ __launch_bounds__(512, 4) void qm_fused(
    const float* __restrict__ x,
    const float* __restrict__ w1,   // (784,32) row-major
    const float* __restrict__ b1,
    const float* __restrict__ lg,
    const float* __restrict__ lb,
    const float* __restrict__ w2,   // (32,4) row-major
    const float* __restrict__ b2,
    const float* __restrict__ pb,   // post_b (2,)
    float* __restrict__ out,        // (B,2)
    int B) {
  __shared__ __align__(16) float stag[8][128];        // 512B weight tile/wave
  __shared__ float part[3 * RPB * 33];                // split-K partials, padded

  const int tid  = threadIdx.x;
  const int w    = tid >> 6;
  const int lane = tid & 63;
  const int chunk = w >> 1;                  // 0..3, wave-uniform
  const int rloc  = ((w & 1) << 6) | lane;   // 0..127
  const int rglob = blockIdx.x * RPB + rloc;

  const float4* __restrict__ xr4 =
      reinterpret_cast<const float4*>(x + (size_t)rglob * 784 + chunk * KCH);
  const float* __restrict__ wbase = w1 + chunk * KCH * 32;   // wave-uniform
  float* __restrict__ st = &stag[w][0];

  float acc[32];
#pragma unroll
  for (int h = 0; h < 32; ++h) acc[h] = 0.0f;

  // prologue prefetch: x float4 of micro 0, weight tile 0 (2 floats/lane)
  float4 xp = xr4[0];
  float2 wp = *reinterpret_cast<const float2*>(wbase + lane * 2);

#pragma unroll 1
  for (int m = 0; m < NMICRO; ++m) {
    // commit weight tile m (128 floats) to this wave's LDS slot
    *reinterpret_cast<float2*>(st + lane * 2) = wp;          // ds_write_b64
    const float4 xc = xp;
    if (m < NMICRO - 1) {                                    // prefetch m+1
      xp = xr4[m + 1];
      wp = *reinterpret_cast<const float2*>(wbase + (m + 1) * 128 + lane * 2);
    }
    const float xs[4] = {xc.x, xc.y, xc.z, xc.w};
#pragma unroll
    for (int kk = 0; kk < 4; ++kk) {
      const float xv = xs[kk];
#pragma unroll
      for (int h4 = 0; h4 < 8; ++h4) {
        // wave-uniform address -> LDS broadcast read, no conflict
        const float4 wv = *reinterpret_cast<const float4*>(st + kk * 32 + h4 * 4);
        acc[h4 * 4 + 0] = fmaf(wv.x, xv, acc[h4 * 4 + 0]);
        acc[h4 * 4 + 1] = fmaf(wv.y, xv, acc[h4 * 4 + 1]);
        acc[h4 * 4 + 2] = fmaf(wv.z, xv, acc[h4 * 4 + 2]);
        acc[h4 * 4 + 3] = fmaf(wv.w, xv, acc[h4 * 4 + 3]);
      }
    }
  }

  // --- split-K reduction: chunks 1..3 park partials in LDS ---
  if (chunk > 0) {
    float* p = &part[((chunk - 1) * RPB + rloc) * 33];
#pragma unroll
    for (int h = 0; h < 32; ++h) p[h] = acc[h];   // stride 33: conflict-free
  }
  __syncthreads();

  if (tid < RPB) {   // waves 0-1 == chunk 0, rloc == tid
#pragma unroll
    for (int c = 0; c < 3; ++c) {
      const float* p = &part[(c * RPB + tid) * 33];
#pragma unroll
      for (int h = 0; h < 32; ++h) acc[h] += p[h];
    }

    // --- bias + relu + layernorm ---
    float mu = 0.0f, sq = 0.0f;
#pragma unroll
    for (int h = 0; h < 32; ++h) {
      float v = fmaxf(acc[h] + b1[h], 0.0f);
      acc[h] = v;
      mu += v;
      sq += v * v;
    }
    mu *= (1.0f / 32.0f);
    sq *= (1.0f / 32.0f);
    const float inv = rsqrtf(sq - mu * mu + 1e-5f);

    // --- z = tanh(hn @ W2 + b2) -> angles -> single-qubit states ---
    float z[4] = {b2[0], b2[1], b2[2], b2[3]};
#pragma unroll
    for (int h = 0; h < 32; ++h) {
      const float hn = (acc[h] - mu) * inv * lg[h] + lb[h];
#pragma unroll
      for (int j = 0; j < 4; ++j) z[j] = fmaf(hn, w2[h * 4 + j], z[j]);
    }
    float cq[4], sn[4];
#pragma unroll
    for (int j = 0; j < 4; ++j) {
      const float half = tanhf(z[j]) * 1.5707963267948966f;
      __sincosf(half, &sn[j], &cq[j]);
    }

    // --- psi: 4-fold kron, qubit 0 = MSB ---
    float psi[16];
#pragma unroll
    for (int b = 0; b < 16; ++b) {
      float p = ((b >> 3) & 1) ? sn[0] : cq[0];
      p *= ((b >> 2) & 1) ? sn[1] : cq[1];
      p *= ((b >> 1) & 1) ? sn[2] : cq[2];
      p *= (b & 1) ? sn[3] : cq[3];
      psi[b] = p;
    }

    // --- out_t = pb_t + sum_j Q[j][t] * |U_j . psi|^2 ---
    float o0 = pb[0], o1 = pb[1];
#pragma unroll
    for (int j = 0; j < 16; ++j) {
      float re = 0.0f, im = 0.0f;
#pragma unroll
      for (int k = 0; k < 16; ++k) {
        re = fmaf(g_Ur[j * 16 + k], psi[k], re);
        im = fmaf(g_Ui[j * 16 + k], psi[k], im);
      }
      const float p = re * re + im * im;
      o0 = fmaf(g_Q[j * 2 + 0], p, o0);
      o1 = fmaf(g_Q[j * 2 + 1], p, o1);
    }
    const int rg = blockIdx.x * RPB + tid;
    reinterpret_cast<float2*>(out)[rg] = make_float2(o0, o1);
  }
}

// --------------------------- launcher --------------------------------------
extern "C" void kernel_launch(void* const* d_in, const int* in_sizes, int n_in,
                              void* d_out, int out_size, void* d_ws, size_t ws_size,
                              hipStream_t stream) {
  const float* x  = (const float*)d_in[0];
  const float* w1 = (const float*)d_in[1];
  const float* b1 = (const float*)d_in[2];
  const float* lg = (const float*)d_in[3];
  const float* lb = (const float*)d_in[4];
  const float* w2 = (const float*)d_in[5];
  const float* b2 = (const float*)d_in[6];
  const float* sw = (const float*)d_in[7];
  const float* tw = (const float*)d_in[8];
  const float* pw = (const float*)d_in[9];
  const float* pb = (const float*)d_in[10];
  float* out = (float*)d_out;

  const int B = in_sizes[0] / 784;   // 65536, divisible by 128

  hipLaunchKernelGGL(build_unitary, dim3(1), dim3(256), 0, stream, sw, tw, pw);
  hipLaunchKernelGGL(qm_fused, dim3(B / RPB), dim3(512), 0, stream,
                     x, w1, b1, lg, lb, w2, b2, pb, out, B);
}